// Round 1
// 22914.250 us; speedup vs baseline: 1.0707x; 1.0707x over previous
//
#include <hip/hip_runtime.h>

// GRU: B=32, T=2048, I=H=512. Persistent 32-workgroup kernel.
// wg g owns h-columns [g*16, g*16+16). Weight slabs (48 rows each of W_hh and
// W_ih, bf16) live in VGPRs as MFMA A-fragments.
//
// h exchange: tag-in-word protocol through a 4-slot ring in ws:
//   u64 hx[4][32][256]; word = { hi32: 0x80000000+t, lo32: 2x bf16 h }
// Producer fires one relaxed agent-scope u64 store per thread (no vmcnt drain,
// no flags). Consumer polls the data words directly — a single LLC round trip
// replaces the old store-drain + flag-store + flag-poll + data-load chain.
// u64 load/store atomicity makes each word self-validating.

#define T_SEQ 2048
#define BATCH 32
#define ISZ 512
#define HSZ 512
#define NG 32      // workgroups
#define CW 16      // h-columns per wg
#define KP 520     // padded LDS row (bf16 elems): stride 1040 B
#define SLOTS 4    // ring depth (reuse distance 4 >> max WG lag of 1)
#define TAGB 0x80000000u

typedef short bf16x8 __attribute__((ext_vector_type(8)));
typedef float f32x4 __attribute__((ext_vector_type(4)));

__device__ __forceinline__ unsigned short f2bf(float f) {
  unsigned int u = __float_as_uint(f);
  unsigned int r = u + 0x7FFFu + ((u >> 16) & 1u);  // RTNE
  return (unsigned short)(r >> 16);
}

// Stage 32 rows x 512 f32 -> bf16 LDS [b][k]. Plain cached loads (read-only src).
__device__ __forceinline__ void stage_plain(const float* base, long rowStride,
                                            unsigned short (*Bst)[KP], int tid) {
  if (tid < 256) {
    const int b = tid >> 3, part = tid & 7;
    const float* src = base + (long)b * rowStride;
#pragma unroll
    for (int i = 0; i < 16; ++i) {
      const int c16 = i * 8 + part;  // 16B chunk id, 0..127
      const float4 f = *(const float4*)(src + c16 * 4);
      ushort4 u;
      u.x = f2bf(f.x); u.y = f2bf(f.y); u.z = f2bf(f.z); u.w = f2bf(f.w);
      *(ushort4*)(&Bst[b][c16 * 4]) = u;
    }
  }
}

// Poll the exchange slot until every word carries `want`, then unpack bf16
// pairs straight into LDS (no conversion needed — payload is already bf16).
__device__ __forceinline__ void stage_hx(const unsigned long long* slot,
                                         const unsigned int want,
                                         unsigned short (*Bst)[KP], int tid) {
  if (tid < 256) {
    const int b = tid >> 3, part = tid & 7;
    const unsigned long long* src = slot + (long)b * (HSZ / 2) + part;
    unsigned long long tmp[32];
#pragma unroll
    for (int i = 0; i < 32; ++i)
      tmp[i] = __hip_atomic_load(src + i * 8, __ATOMIC_RELAXED,
                                 __HIP_MEMORY_SCOPE_AGENT);
    for (;;) {
      bool ok = true;
#pragma unroll
      for (int i = 0; i < 32; ++i) {
        if ((unsigned int)(tmp[i] >> 32) != want) {
          ok = false;
          tmp[i] = __hip_atomic_load(src + i * 8, __ATOMIC_RELAXED,
                                     __HIP_MEMORY_SCOPE_AGENT);
        }
      }
      if (ok) break;  // reloaded words re-checked on the next iteration
    }
#pragma unroll
    for (int i = 0; i < 32; ++i) {
      const int c = i * 8 + part;  // u64 index 0..255 -> cols {2c, 2c+1}
      *(unsigned int*)(&Bst[b][c * 2]) = (unsigned int)tmp[i];
    }
  }
}

// 16x16 output tile: A-slab (16 K-frags in regs) x B (h/input staged in LDS).
__device__ __forceinline__ f32x4 mfma_slab(const bf16x8* a,
                                           unsigned short (*Bst)[KP],
                                           int bt, int n16, int quad) {
  f32x4 acc = {0.f, 0.f, 0.f, 0.f};
#pragma unroll
  for (int kk = 0; kk < 16; ++kk) {
    const bf16x8 bf = *(const bf16x8*)(&Bst[bt * 16 + n16][kk * 32 + quad * 8]);
    acc = __builtin_amdgcn_mfma_f32_16x16x32_bf16(a[kk], bf, acc, 0, 0, 0);
  }
  return acc;
}

__global__ __launch_bounds__(384, 2) void gru_persistent(
    const float* __restrict__ in, const float* __restrict__ h0,
    const float* __restrict__ wih, const float* __restrict__ whh,
    const float* __restrict__ bihp, const float* __restrict__ bhhp,
    float* __restrict__ out, unsigned long long* __restrict__ hx) {
  __shared__ unsigned short Bstage[BATCH][KP];  // B-operand stage (h or input)
  __shared__ float xg[3][CW][33];               // input gates for current t
  __shared__ float hg[3][CW][33];               // hidden gates
  __shared__ float own_h[CW][33];               // fp32 carried state (own slice)
  __shared__ float bih_l[48], bhh_l[48];

  const int tid = threadIdx.x;
  const int g = blockIdx.x;
  const int c0 = g * CW;
  const int lane = tid & 63, wid = tid >> 6;
  const int n16 = lane & 15, quad = lane >> 4;
  const int rt = wid % 3, bt = wid / 3;  // gate index, batch tile

  // ---- prologue: biases for this wg's 48 rows ----
  if (tid < 48) bih_l[tid] = bihp[(tid >> 4) * HSZ + c0 + (tid & 15)];
  else if (tid >= 64 && tid < 112) {
    const int lr = tid - 64;
    bhh_l[lr] = bhhp[(lr >> 4) * HSZ + c0 + (lr & 15)];
  }

  // ---- zero own ring entries (cross-launch safety), drain before 1st tag ----
  if (tid < 256) {
    const int b = tid >> 3, j = tid & 7;
#pragma unroll
    for (int s = 0; s < SLOTS; ++s)
      __hip_atomic_store(hx + (long)s * BATCH * (HSZ / 2) + b * (HSZ / 2) + g * 8 + j,
                         0ULL, __ATOMIC_RELAXED, __HIP_MEMORY_SCOPE_AGENT);
  }

  // ---- weight slabs -> registers (MFMA A-frag layout: m=lane&15, k=quad*8+j)
  bf16x8 a_hh[16], a_ih[16];
  {
    const long grow = rt * HSZ + c0 + n16;
    const float* wr_h = whh + grow * HSZ;
    const float* wr_i = wih + grow * ISZ;
#pragma unroll
    for (int kk = 0; kk < 16; ++kk) {
      const int k0 = kk * 32 + quad * 8;
      float4 f0 = *(const float4*)(wr_h + k0);
      float4 f1 = *(const float4*)(wr_h + k0 + 4);
      bf16x8 v;
      v[0] = (short)f2bf(f0.x); v[1] = (short)f2bf(f0.y);
      v[2] = (short)f2bf(f0.z); v[3] = (short)f2bf(f0.w);
      v[4] = (short)f2bf(f1.x); v[5] = (short)f2bf(f1.y);
      v[6] = (short)f2bf(f1.z); v[7] = (short)f2bf(f1.w);
      a_hh[kk] = v;
      f0 = *(const float4*)(wr_i + k0);
      f1 = *(const float4*)(wr_i + k0 + 4);
      v[0] = (short)f2bf(f0.x); v[1] = (short)f2bf(f0.y);
      v[2] = (short)f2bf(f0.z); v[3] = (short)f2bf(f0.w);
      v[4] = (short)f2bf(f1.x); v[5] = (short)f2bf(f1.y);
      v[6] = (short)f2bf(f1.z); v[7] = (short)f2bf(f1.w);
      a_ih[kk] = v;
    }
  }
  // Zero-writes must be at LLC before any tagged store becomes visible.
  asm volatile("s_waitcnt vmcnt(0)" ::: "memory");

  // ---- xg for t=0 ----
  stage_plain(in, (long)T_SEQ * ISZ, Bstage, tid);
  __syncthreads();
  {
    f32x4 acc = mfma_slab(a_ih, Bstage, bt, n16, quad);
#pragma unroll
    for (int r = 0; r < 4; ++r)
      xg[rt][quad * 4 + r][bt * 16 + n16] = acc[r] + bih_l[rt * 16 + quad * 4 + r];
  }
  __syncthreads();

  for (int t = 0; t < T_SEQ; ++t) {
    // ---- Phase A: obtain h(t-1) into Bstage ----
    if (t == 0) {
      stage_plain(h0, HSZ, Bstage, tid);
      if (tid < 256) {
        const int b = tid >> 3, j = tid & 7;
        own_h[2 * j][b] = h0[b * HSZ + c0 + 2 * j];
        own_h[2 * j + 1][b] = h0[b * HSZ + c0 + 2 * j + 1];
      }
    } else {
      stage_hx(hx + (long)((t - 1) & (SLOTS - 1)) * BATCH * (HSZ / 2),
               TAGB + (unsigned)(t - 1), Bstage, tid);
    }
    __syncthreads();

    // ---- Phase B: hg = W_hh(slab) @ h ----
    {
      f32x4 acc = mfma_slab(a_hh, Bstage, bt, n16, quad);
#pragma unroll
      for (int r = 0; r < 4; ++r)
        hg[rt][quad * 4 + r][bt * 16 + n16] = acc[r];
    }
    __syncthreads();

    // ---- Phase C: gates + publish h slice (tagged, fire-and-forget) ----
    if (tid < 256) {
      const int b = tid >> 3, j = tid & 7;
      float h2[2];
#pragma unroll
      for (int jj = 0; jj < 2; ++jj) {
        const int col = 2 * j + jj;
        const float xr = xg[0][col][b], xz = xg[1][col][b], xn = xg[2][col][b];
        const float hr = hg[0][col][b] + bhh_l[col];
        const float hz = hg[1][col][b] + bhh_l[16 + col];
        const float hn = hg[2][col][b] + bhh_l[32 + col];
        const float r = 1.f / (1.f + __expf(-(xr + hr)));
        const float z = 1.f / (1.f + __expf(-(xz + hz)));
        const float aa = xn + r * hn;
        const float e = __expf(-2.f * fabsf(aa));
        float th = (1.f - e) / (1.f + e);
        th = copysignf(th, aa);
        const float hp = own_h[col][b];
        const float hnew = (1.f - z) * th + z * hp;
        own_h[col][b] = hnew;
        h2[jj] = hnew;
      }
      // tagged bf16 pair -> exchange ring (single self-validating u64)
      const unsigned int lo =
          (unsigned int)f2bf(h2[0]) | ((unsigned int)f2bf(h2[1]) << 16);
      const unsigned long long val =
          ((unsigned long long)(TAGB + (unsigned)t) << 32) | lo;
      __hip_atomic_store(hx + (long)(t & (SLOTS - 1)) * BATCH * (HSZ / 2) +
                             b * (HSZ / 2) + g * 8 + j,
                         val, __ATOMIC_RELAXED, __HIP_MEMORY_SCOPE_AGENT);
      // fp32 result -> out (write-only now; off the critical path)
      const unsigned long long o2 =
          ((unsigned long long)__float_as_uint(h2[1]) << 32) |
          (unsigned long long)__float_as_uint(h2[0]);
      __builtin_nontemporal_store(
          o2, (unsigned long long*)(out + (long)b * T_SEQ * HSZ +
                                    (long)t * HSZ + c0 + 2 * j));
    }
    __syncthreads();  // xg about to be overwritten by Phase D

    // ---- Phase D: xg for t+1 (input side; overlaps peers' store latency) ----
    if (t + 1 < T_SEQ) {
      stage_plain(in + (long)(t + 1) * ISZ, (long)T_SEQ * ISZ, Bstage, tid);
      __syncthreads();
      f32x4 acc = mfma_slab(a_ih, Bstage, bt, n16, quad);
#pragma unroll
      for (int r = 0; r < 4; ++r)
        xg[rt][quad * 4 + r][bt * 16 + n16] =
            acc[r] + bih_l[rt * 16 + quad * 4 + r];
      __syncthreads();
    }
  }
}

extern "C" void kernel_launch(void* const* d_in, const int* in_sizes, int n_in,
                              void* d_out, int out_size, void* d_ws, size_t ws_size,
                              hipStream_t stream) {
  const float* in  = (const float*)d_in[0];
  const float* h0  = (const float*)d_in[1];
  const float* wih = (const float*)d_in[2];
  const float* whh = (const float*)d_in[3];
  const float* bih = (const float*)d_in[4];
  const float* bhh = (const float*)d_in[5];
  float* out = (float*)d_out;
  unsigned long long* hx = (unsigned long long*)d_ws;  // 4*32*256*8 = 256 KB

  gru_persistent<<<dim3(NG), dim3(384), 0, stream>>>(in, h0, wih, whh, bih, bhh,
                                                     out, hx);
}

// Round 3
// 14269.933 us; speedup vs baseline: 1.7193x; 1.6058x over previous
//
#include <hip/hip_runtime.h>

// GRU: B=32, T=2048, I=H=512. Persistent 32-workgroup kernel.
// wg g owns h-columns [g*16, g*16+16). Weight slabs (48 rows each of W_hh and
// W_ih, bf16) live in VGPRs/AGPRs as MFMA A-fragments.
//
// h exchange: tag-in-word protocol through a 4-slot ring in ws:
//   u64 hx[4][32][256]; word = { hi32: 0x80000000+t, lo32: 2x bf16 h }
// Producer fires one relaxed agent-scope u64 store per thread; consumer polls
// the data words directly (self-validating u64), 1 LLC round trip per round.
//
// Input-side overlap WITHOUT register cost (round-2's pf[16] registers caused
// a spill blowup): in(t+1) is staged at the TOP of each step via async
// global_load_lds into an f32 LDS buffer Bxf; its latency hides under the
// h-poll. During Phase B (under the hh-MFMA) the staging threads convert
// Bxf (f32) -> Bx (bf16) through fast LDS reads. Phase D is MFMA-only.

#define T_SEQ 2048
#define BATCH 32
#define ISZ 512
#define HSZ 512
#define NG 32      // workgroups
#define CW 16      // h-columns per wg
#define KP 520     // padded LDS row (bf16 elems): stride 1040 B
#define XF 520     // Bxf row stride in f32 (2080 B): 16B-aligned, 2-way-free banks
#define SLOTS 4    // ring depth (reuse distance 4 >> max WG lag of 1)
#define TAGB 0x80000000u

typedef short bf16x8 __attribute__((ext_vector_type(8)));
typedef float f32x4 __attribute__((ext_vector_type(4)));

__device__ __forceinline__ unsigned short f2bf(float f) {
  unsigned int u = __float_as_uint(f);
  unsigned int r = u + 0x7FFFu + ((u >> 16) & 1u);  // RTNE
  return (unsigned short)(r >> 16);
}

// Async global->LDS, 16 B per lane. lds dest must be wave-uniform; HW writes
// ldsbase + lane*16. gsrc is per-lane.
__device__ __forceinline__ void gl2lds16(const float* gsrc, void* lds) {
  __builtin_amdgcn_global_load_lds(
      (const __attribute__((address_space(1))) void*)gsrc,
      (__attribute__((address_space(3))) void*)lds, 16, 0, 0);
}

// Stage 32 rows x 512 f32 -> bf16 LDS [b][k]. Plain cached loads. Used only
// off the steady-state path (prologue, t=0).
__device__ __forceinline__ void stage_plain(const float* base, long rowStride,
                                            unsigned short (*Bst)[KP], int tid) {
  if (tid < 256) {
    const int b = tid >> 3, part = tid & 7;
    const float* src = base + (long)b * rowStride;
#pragma unroll
    for (int i = 0; i < 16; ++i) {
      const int c16 = i * 8 + part;  // 16B chunk id, 0..127
      const float4 f = *(const float4*)(src + c16 * 4);
      ushort4 u;
      u.x = f2bf(f.x); u.y = f2bf(f.y); u.z = f2bf(f.z); u.w = f2bf(f.w);
      *(ushort4*)(&Bst[b][c16 * 4]) = u;
    }
  }
}

// Poll the exchange slot until every word carries `want`, then unpack bf16
// pairs straight into LDS. Branchless rounds: issue all 32 loads, wait once,
// OR-reduce the tag mismatches, retry-all on failure.
__device__ __forceinline__ void stage_hx(const unsigned long long* slot,
                                         const unsigned int want,
                                         unsigned short (*Bst)[KP], int tid) {
  if (tid < 256) {
    const int b = tid >> 3, part = tid & 7;
    const unsigned long long* src = slot + (long)b * (HSZ / 2) + part;
    unsigned long long tmp[32];
#pragma unroll
    for (int i = 0; i < 32; ++i)
      tmp[i] = __hip_atomic_load(src + i * 8, __ATOMIC_RELAXED,
                                 __HIP_MEMORY_SCOPE_AGENT);
    for (;;) {
      unsigned int bad = 0;
#pragma unroll
      for (int i = 0; i < 32; ++i)
        bad |= ((unsigned int)(tmp[i] >> 32)) ^ want;
      if (bad == 0) break;
#pragma unroll
      for (int i = 0; i < 32; ++i)
        tmp[i] = __hip_atomic_load(src + i * 8, __ATOMIC_RELAXED,
                                   __HIP_MEMORY_SCOPE_AGENT);
    }
#pragma unroll
    for (int i = 0; i < 32; ++i) {
      const int c = i * 8 + part;  // u64 index 0..255 -> cols {2c, 2c+1}
      *(unsigned int*)(&Bst[b][c * 2]) = (unsigned int)tmp[i];
    }
  }
}

// 16x16 output tile: A-slab (16 K-frags in regs) x B (staged in LDS).
__device__ __forceinline__ f32x4 mfma_slab(const bf16x8* a,
                                           unsigned short (*Bst)[KP],
                                           int bt, int n16, int quad) {
  f32x4 acc = {0.f, 0.f, 0.f, 0.f};
#pragma unroll
  for (int kk = 0; kk < 16; ++kk) {
    const bf16x8 bf = *(const bf16x8*)(&Bst[bt * 16 + n16][kk * 32 + quad * 8]);
    acc = __builtin_amdgcn_mfma_f32_16x16x32_bf16(a[kk], bf, acc, 0, 0, 0);
  }
  return acc;
}

__global__ __launch_bounds__(384, 1) void gru_persistent(
    const float* __restrict__ in, const float* __restrict__ h0,
    const float* __restrict__ wih, const float* __restrict__ whh,
    const float* __restrict__ bihp, const float* __restrict__ bhhp,
    float* __restrict__ out, unsigned long long* __restrict__ hx) {
  __shared__ unsigned short Bh[BATCH][KP];  // h operand (bf16)
  __shared__ unsigned short Bx[BATCH][KP];  // input operand (bf16)
  __shared__ float Bxf[BATCH][XF];          // raw f32 input (global_load_lds dest)
  __shared__ float xg[3][CW][33];           // input gates for current t
  __shared__ float hg[3][CW][33];           // hidden gates
  __shared__ float own_h[CW][33];           // fp32 carried state (own slice)
  __shared__ float bih_l[48], bhh_l[48];

  const int tid = threadIdx.x;
  const int g = blockIdx.x;
  const int c0 = g * CW;
  const int lane = tid & 63, wid = tid >> 6;
  const int n16 = lane & 15, quad = lane >> 4;
  const int rt = wid % 3, bt = wid / 3;  // gate index, batch tile
  const int sb = tid >> 3, sp = tid & 7; // staging row / part (tid<256)

  // ---- prologue: biases for this wg's 48 rows ----
  if (tid < 48) bih_l[tid] = bihp[(tid >> 4) * HSZ + c0 + (tid & 15)];
  else if (tid >= 64 && tid < 112) {
    const int lr = tid - 64;
    bhh_l[lr] = bhhp[(lr >> 4) * HSZ + c0 + (lr & 15)];
  }

  // ---- zero own ring entries (cross-launch safety) ----
  if (tid < 256) {
#pragma unroll
    for (int s = 0; s < SLOTS; ++s)
      __hip_atomic_store(hx + (long)s * BATCH * (HSZ / 2) + sb * (HSZ / 2) + g * 8 + sp,
                         0ULL, __ATOMIC_RELAXED, __HIP_MEMORY_SCOPE_AGENT);
  }

  // ---- weight slabs -> registers (MFMA A-frag layout: m=lane&15, k=quad*8+j)
  bf16x8 a_hh[16], a_ih[16];
  {
    const long grow = rt * HSZ + c0 + n16;
    const float* wr_h = whh + grow * HSZ;
    const float* wr_i = wih + grow * ISZ;
#pragma unroll
    for (int kk = 0; kk < 16; ++kk) {
      const int k0 = kk * 32 + quad * 8;
      float4 f0 = *(const float4*)(wr_h + k0);
      float4 f1 = *(const float4*)(wr_h + k0 + 4);
      bf16x8 v;
      v[0] = (short)f2bf(f0.x); v[1] = (short)f2bf(f0.y);
      v[2] = (short)f2bf(f0.z); v[3] = (short)f2bf(f0.w);
      v[4] = (short)f2bf(f1.x); v[5] = (short)f2bf(f1.y);
      v[6] = (short)f2bf(f1.z); v[7] = (short)f2bf(f1.w);
      a_hh[kk] = v;
      f0 = *(const float4*)(wr_i + k0);
      f1 = *(const float4*)(wr_i + k0 + 4);
      v[0] = (short)f2bf(f0.x); v[1] = (short)f2bf(f0.y);
      v[2] = (short)f2bf(f0.z); v[3] = (short)f2bf(f0.w);
      v[4] = (short)f2bf(f1.x); v[5] = (short)f2bf(f1.y);
      v[6] = (short)f2bf(f1.z); v[7] = (short)f2bf(f1.w);
      a_ih[kk] = v;
    }
  }
  // Zero-writes must be at LLC before any tagged store becomes visible.
  asm volatile("s_waitcnt vmcnt(0)" ::: "memory");

  // ---- xg for t=0 ----
  stage_plain(in, (long)T_SEQ * ISZ, Bx, tid);
  __syncthreads();
  {
    f32x4 acc = mfma_slab(a_ih, Bx, bt, n16, quad);
#pragma unroll
    for (int r = 0; r < 4; ++r)
      xg[rt][quad * 4 + r][bt * 16 + n16] = acc[r] + bih_l[rt * 16 + quad * 4 + r];
  }
  __syncthreads();

  for (int t = 0; t < T_SEQ; ++t) {
    // ---- issue async staging of in(t+1) -> Bxf (latency hides under poll) ----
    if (t + 1 < T_SEQ) {
      const float* tb = in + (long)(t + 1) * ISZ + (lane << 2);
#pragma unroll
      for (int b = wid; b < BATCH; b += 6) {
        const float* src = tb + (long)b * T_SEQ * ISZ;
        gl2lds16(src, &Bxf[b][0]);          // f32[0..255]
        gl2lds16(src + 256, &Bxf[b][256]);  // f32[256..511]
      }
    }

    // ---- Phase A: obtain h(t-1) into Bh ----
    if (t == 0) {
      stage_plain(h0, HSZ, Bh, tid);
      if (tid < 256) {
        own_h[2 * sp][sb] = h0[sb * HSZ + c0 + 2 * sp];
        own_h[2 * sp + 1][sb] = h0[sb * HSZ + c0 + 2 * sp + 1];
      }
    } else {
      stage_hx(hx + (long)((t - 1) & (SLOTS - 1)) * BATCH * (HSZ / 2),
               TAGB + (unsigned)(t - 1), Bh, tid);
    }
    // Drain this wave's staging issues; barrier orders all waves' staging
    // before any Bxf reader (hipcc also drains vmcnt at __syncthreads).
    asm volatile("s_waitcnt vmcnt(0)" ::: "memory");
    __syncthreads();

    // ---- Phase B: hg = W_hh(slab) @ h ; convert Bxf(f32) -> Bx(bf16) ----
    {
      f32x4 acc = mfma_slab(a_hh, Bh, bt, n16, quad);
#pragma unroll
      for (int r = 0; r < 4; ++r)
        hg[rt][quad * 4 + r][bt * 16 + n16] = acc[r];
    }
    if (t + 1 < T_SEQ && tid < 256) {
#pragma unroll
      for (int i = 0; i < 16; ++i) {
        const int c16 = i * 8 + sp;
        const float4 f = *(const float4*)(&Bxf[sb][c16 * 4]);
        ushort4 u;
        u.x = f2bf(f.x); u.y = f2bf(f.y); u.z = f2bf(f.z); u.w = f2bf(f.w);
        *(ushort4*)(&Bx[sb][c16 * 4]) = u;
      }
    }
    __syncthreads();

    // ---- Phase C: gates + publish h slice (tagged, fire-and-forget) ----
    if (tid < 256) {
      float h2[2];
#pragma unroll
      for (int jj = 0; jj < 2; ++jj) {
        const int col = 2 * sp + jj;
        const float xr = xg[0][col][sb], xz = xg[1][col][sb], xn = xg[2][col][sb];
        const float hr = hg[0][col][sb] + bhh_l[col];
        const float hz = hg[1][col][sb] + bhh_l[16 + col];
        const float hn = hg[2][col][sb] + bhh_l[32 + col];
        const float r = 1.f / (1.f + __expf(-(xr + hr)));
        const float z = 1.f / (1.f + __expf(-(xz + hz)));
        const float aa = xn + r * hn;
        const float e = __expf(-2.f * fabsf(aa));
        float th = (1.f - e) / (1.f + e);
        th = copysignf(th, aa);
        const float hp = own_h[col][sb];
        const float hnew = (1.f - z) * th + z * hp;
        own_h[col][sb] = hnew;
        h2[jj] = hnew;
      }
      // tagged bf16 pair -> exchange ring (single self-validating u64)
      const unsigned int lo =
          (unsigned int)f2bf(h2[0]) | ((unsigned int)f2bf(h2[1]) << 16);
      const unsigned long long val =
          ((unsigned long long)(TAGB + (unsigned)t) << 32) | lo;
      __hip_atomic_store(hx + (long)(t & (SLOTS - 1)) * BATCH * (HSZ / 2) +
                             sb * (HSZ / 2) + g * 8 + sp,
                         val, __ATOMIC_RELAXED, __HIP_MEMORY_SCOPE_AGENT);
      // fp32 result -> out (write-only; off the critical path)
      const unsigned long long o2 =
          ((unsigned long long)__float_as_uint(h2[1]) << 32) |
          (unsigned long long)__float_as_uint(h2[0]);
      __builtin_nontemporal_store(
          o2, (unsigned long long*)(out + (long)sb * T_SEQ * HSZ +
                                    (long)t * HSZ + c0 + 2 * sp));
    }
    __syncthreads();  // xg about to be overwritten by Phase D

    // ---- Phase D: xg(t+1) = W_ih(slab) @ in(t+1)  (Bx already staged) ----
    if (t + 1 < T_SEQ) {
      f32x4 acc = mfma_slab(a_ih, Bx, bt, n16, quad);
#pragma unroll
      for (int r = 0; r < 4; ++r)
        xg[rt][quad * 4 + r][bt * 16 + n16] =
            acc[r] + bih_l[rt * 16 + quad * 4 + r];
      __syncthreads();
    }
  }
}

extern "C" void kernel_launch(void* const* d_in, const int* in_sizes, int n_in,
                              void* d_out, int out_size, void* d_ws, size_t ws_size,
                              hipStream_t stream) {
  const float* in  = (const float*)d_in[0];
  const float* h0  = (const float*)d_in[1];
  const float* wih = (const float*)d_in[2];
  const float* whh = (const float*)d_in[3];
  const float* bih = (const float*)d_in[4];
  const float* bhh = (const float*)d_in[5];
  float* out = (float*)d_out;
  unsigned long long* hx = (unsigned long long*)d_ws;  // 4*32*256*8 = 256 KB

  gru_persistent<<<dim3(NG), dim3(384), 0, stream>>>(in, h0, wih, whh, bih, bhh,
                                                     out, hx);
}

// Round 4
// 13040.715 us; speedup vs baseline: 1.8814x; 1.0943x over previous
//
#include <hip/hip_runtime.h>

// GRU: B=32, T=2048, I=H=512. Persistent 32-workgroup kernel, all 32 WGs
// self-placed on ONE XCD so the h-exchange runs through that XCD's L2
// (~100-200ns RT) instead of the die-level LLC (~1-2us RT).
//
// Placement protocol (correctness does NOT depend on dispatch mapping):
//   grid = 256 blocks; LDS 148KB forces 1 block/CU so all 256 CUs get one.
//   Each block reads HW_REG_XCC_ID; the first block CASes (xcc+1) into a
//   zeroed control word; blocks on the winning XCD claim slots 0..31 and
//   persist; the other 224 blocks exit immediately.
//
// h exchange: tag-in-word protocol through a 2-slot ring in ws:
//   u64 hx[2][32][256]; word = { hi32: 0x80000000+t, lo32: 2x bf16 h }
// Producer: one plain (workgroup-scope) u64 store -> lands in local L2.
// Consumer: 32 inline-asm `global_load_dwordx2 ... sc0` (bypass L1, read L2),
// self-validating tags, one L2 RT per retry round. Rule-#18 discipline:
// waitcnt -> sched_barrier(0) -> asm pins before the tag check.
//
// Input-side overlap: in(t+1) staged via async global_load_lds into f32 LDS
// at the top of each step (latency hides under the poll); converted to bf16
// under the hh-MFMA in Phase B.

#define T_SEQ 2048
#define BATCH 32
#define ISZ 512
#define HSZ 512
#define NG 32      // participating workgroups
#define CW 16      // h-columns per wg
#define KP 520     // padded LDS row (bf16 elems): stride 1040 B
#define XF 520     // Bxf row stride in f32
#define SLOTS 2    // ring depth (double-buffer; safe per barrier argument)
#define TAGB 0x80000000u
#define CTL_BYTES 4096

typedef short bf16x8 __attribute__((ext_vector_type(8)));
typedef float f32x4 __attribute__((ext_vector_type(4)));

__device__ __forceinline__ unsigned short f2bf(float f) {
  unsigned int u = __float_as_uint(f);
  unsigned int r = u + 0x7FFFu + ((u >> 16) & 1u);  // RTNE
  return (unsigned short)(r >> 16);
}

// Async global->LDS, 16 B per lane. lds dest wave-uniform; HW writes
// ldsbase + lane*16. gsrc per-lane. Default policy -> cached in L2 (dedup
// across the 32 co-located WGs).
__device__ __forceinline__ void gl2lds16(const float* gsrc, void* lds) {
  __builtin_amdgcn_global_load_lds(
      (const __attribute__((address_space(1))) void*)gsrc,
      (__attribute__((address_space(3))) void*)lds, 16, 0, 0);
}

// Stage 32 rows x 512 f32 -> bf16 LDS [b][k]. Off the steady-state path.
__device__ __forceinline__ void stage_plain(const float* base, long rowStride,
                                            unsigned short (*Bst)[KP], int tid) {
  if (tid < 256) {
    const int b = tid >> 3, part = tid & 7;
    const float* src = base + (long)b * rowStride;
#pragma unroll
    for (int i = 0; i < 16; ++i) {
      const int c16 = i * 8 + part;
      const float4 f = *(const float4*)(src + c16 * 4);
      ushort4 u;
      u.x = f2bf(f.x); u.y = f2bf(f.y); u.z = f2bf(f.z); u.w = f2bf(f.w);
      *(ushort4*)(&Bst[b][c16 * 4]) = u;
    }
  }
}

// Issue 32 L1-bypassing (sc0) u64 loads: SGPR base + per-lane voffset +
// immediate offsets. Values land in tmp[]; caller must s_waitcnt before use.
__device__ __forceinline__ void issue32(unsigned long long* tmp, unsigned voff,
                                        const unsigned long long* base) {
#define LD1(i)                                                        \
  asm volatile("global_load_dwordx2 %0, %1, %2 offset:%3 sc0"         \
               : "=v"(tmp[i])                                         \
               : "v"(voff), "s"(base), "i"((i) * 64));
  LD1(0)  LD1(1)  LD1(2)  LD1(3)  LD1(4)  LD1(5)  LD1(6)  LD1(7)
  LD1(8)  LD1(9)  LD1(10) LD1(11) LD1(12) LD1(13) LD1(14) LD1(15)
  LD1(16) LD1(17) LD1(18) LD1(19) LD1(20) LD1(21) LD1(22) LD1(23)
  LD1(24) LD1(25) LD1(26) LD1(27) LD1(28) LD1(29) LD1(30) LD1(31)
#undef LD1
}

// Poll the exchange slot until every word carries `want`, then unpack bf16
// pairs straight into LDS. Each retry round = one L2 round trip.
__device__ __forceinline__ void stage_hx(const unsigned long long* slot,
                                         const unsigned int want,
                                         unsigned short (*Bst)[KP], int tid) {
  if (tid < 256) {
    const int b = tid >> 3, part = tid & 7;
    const unsigned voff = (unsigned)((b * (HSZ / 2) + part) * 8);
    unsigned long long tmp[32];
    issue32(tmp, voff, slot);
    for (;;) {
      asm volatile("s_waitcnt vmcnt(0)" ::: "memory");
      __builtin_amdgcn_sched_barrier(0);
#pragma unroll
      for (int i = 0; i < 32; ++i) asm volatile("" : "+v"(tmp[i]));
      unsigned int bad = 0;
#pragma unroll
      for (int i = 0; i < 32; ++i)
        bad |= ((unsigned int)(tmp[i] >> 32)) ^ want;
      if (bad == 0) break;
      issue32(tmp, voff, slot);
    }
#pragma unroll
    for (int i = 0; i < 32; ++i) {
      const int c = i * 8 + part;  // u64 index 0..255 -> cols {2c, 2c+1}
      *(unsigned int*)(&Bst[b][c * 2]) = (unsigned int)tmp[i];
    }
  }
}

// 16x16 output tile: A-slab (16 K-frags in regs) x B (staged in LDS).
__device__ __forceinline__ f32x4 mfma_slab(const bf16x8* a,
                                           unsigned short (*Bst)[KP],
                                           int bt, int n16, int quad) {
  f32x4 acc = {0.f, 0.f, 0.f, 0.f};
#pragma unroll
  for (int kk = 0; kk < 16; ++kk) {
    const bf16x8 bf = *(const bf16x8*)(&Bst[bt * 16 + n16][kk * 32 + quad * 8]);
    acc = __builtin_amdgcn_mfma_f32_16x16x32_bf16(a[kk], bf, acc, 0, 0, 0);
  }
  return acc;
}

__global__ __launch_bounds__(384, 1) void gru_persistent(
    const float* __restrict__ in, const float* __restrict__ h0,
    const float* __restrict__ wih, const float* __restrict__ whh,
    const float* __restrict__ bihp, const float* __restrict__ bhhp,
    float* __restrict__ out, unsigned int* __restrict__ ctl,
    unsigned long long* __restrict__ hx) {
  __shared__ unsigned short Bh[BATCH][KP];  // h operand (bf16)
  __shared__ unsigned short Bx[BATCH][KP];  // input operand (bf16)
  __shared__ float Bxf[BATCH][XF];          // raw f32 input (global_load_lds dest)
  __shared__ float xg[3][CW][33];           // input gates for current t
  __shared__ float hg[3][CW][33];           // hidden gates
  __shared__ float own_h[CW][33];           // fp32 carried state (own slice)
  __shared__ float bih_l[48], bhh_l[48];
  __shared__ int s_ok, s_g;

  const int tid = threadIdx.x;

  // ---- self-placement: participate only if on the winning XCD ----
  // hwreg(HW_REG_XCC_ID=20, offset 0, width 32) -> 20 | 31<<11 = 63508
  const unsigned xcc = __builtin_amdgcn_s_getreg(63508) & 0xFu;
  if (tid == 0) {
    unsigned expected = 0u;
    __hip_atomic_compare_exchange_strong(&ctl[0], &expected, xcc + 1u,
                                         __ATOMIC_RELAXED, __ATOMIC_RELAXED,
                                         __HIP_MEMORY_SCOPE_AGENT);
    const unsigned tgt = (expected == 0u) ? (xcc + 1u) : expected;
    int ok = (tgt == xcc + 1u);
    int gg = 0;
    if (ok)
      gg = (int)__hip_atomic_fetch_add(&ctl[1], 1u, __ATOMIC_RELAXED,
                                       __HIP_MEMORY_SCOPE_AGENT);
    s_ok = ok && (gg < NG);
    s_g = gg;
  }
  __syncthreads();
  if (!s_ok) return;  // uniform per block
  const int g = s_g;

  const int c0 = g * CW;
  const int lane = tid & 63, wid = tid >> 6;
  const int n16 = lane & 15, quad = lane >> 4;
  const int rt = wid % 3, bt = wid / 3;   // gate index, batch tile
  const int sb = tid >> 3, sp = tid & 7;  // staging row / part (tid<256)

  // ---- prologue: biases for this wg's 48 rows ----
  if (tid < 48) bih_l[tid] = bihp[(tid >> 4) * HSZ + c0 + (tid & 15)];
  else if (tid >= 64 && tid < 112) {
    const int lr = tid - 64;
    bhh_l[lr] = bhhp[(lr >> 4) * HSZ + c0 + (lr & 15)];
  }

  // ---- zero own ring entries (kills stale tags from previous launches;
  //      mandatory: last-SLOTS steps of a prior run alias current tags) ----
  if (tid < 256) {
#pragma unroll
    for (int s = 0; s < SLOTS; ++s)
      __hip_atomic_store(hx + (long)s * BATCH * (HSZ / 2) + sb * (HSZ / 2) + g * 8 + sp,
                         0ULL, __ATOMIC_RELAXED, __HIP_MEMORY_SCOPE_WORKGROUP);
  }

  // ---- weight slabs -> registers (MFMA A-frag layout: m=lane&15, k=quad*8+j)
  bf16x8 a_hh[16], a_ih[16];
  {
    const long grow = rt * HSZ + c0 + n16;
    const float* wr_h = whh + grow * HSZ;
    const float* wr_i = wih + grow * ISZ;
#pragma unroll
    for (int kk = 0; kk < 16; ++kk) {
      const int k0 = kk * 32 + quad * 8;
      float4 f0 = *(const float4*)(wr_h + k0);
      float4 f1 = *(const float4*)(wr_h + k0 + 4);
      bf16x8 v;
      v[0] = (short)f2bf(f0.x); v[1] = (short)f2bf(f0.y);
      v[2] = (short)f2bf(f0.z); v[3] = (short)f2bf(f0.w);
      v[4] = (short)f2bf(f1.x); v[5] = (short)f2bf(f1.y);
      v[6] = (short)f2bf(f1.z); v[7] = (short)f2bf(f1.w);
      a_hh[kk] = v;
      f0 = *(const float4*)(wr_i + k0);
      f1 = *(const float4*)(wr_i + k0 + 4);
      v[0] = (short)f2bf(f0.x); v[1] = (short)f2bf(f0.y);
      v[2] = (short)f2bf(f0.z); v[3] = (short)f2bf(f0.w);
      v[4] = (short)f2bf(f1.x); v[5] = (short)f2bf(f1.y);
      v[6] = (short)f2bf(f1.z); v[7] = (short)f2bf(f1.w);
      a_ih[kk] = v;
    }
  }
  // Zero-writes must be in L2 before the first tagged publish.
  asm volatile("s_waitcnt vmcnt(0)" ::: "memory");

  // ---- xg for t=0 ----
  stage_plain(in, (long)T_SEQ * ISZ, Bx, tid);
  __syncthreads();
  {
    f32x4 acc = mfma_slab(a_ih, Bx, bt, n16, quad);
#pragma unroll
    for (int r = 0; r < 4; ++r)
      xg[rt][quad * 4 + r][bt * 16 + n16] = acc[r] + bih_l[rt * 16 + quad * 4 + r];
  }
  __syncthreads();

  for (int t = 0; t < T_SEQ; ++t) {
    // ---- issue async staging of in(t+1) -> Bxf (hides under the poll) ----
    if (t + 1 < T_SEQ) {
      const float* tb = in + (long)(t + 1) * ISZ + (lane << 2);
#pragma unroll
      for (int b = wid; b < BATCH; b += 6) {
        const float* src = tb + (long)b * T_SEQ * ISZ;
        gl2lds16(src, &Bxf[b][0]);
        gl2lds16(src + 256, &Bxf[b][256]);
      }
    }

    // ---- Phase A: obtain h(t-1) into Bh ----
    if (t == 0) {
      stage_plain(h0, HSZ, Bh, tid);
      if (tid < 256) {
        own_h[2 * sp][sb] = h0[sb * HSZ + c0 + 2 * sp];
        own_h[2 * sp + 1][sb] = h0[sb * HSZ + c0 + 2 * sp + 1];
      }
    } else {
      stage_hx(hx + (long)((t - 1) & (SLOTS - 1)) * BATCH * (HSZ / 2),
               TAGB + (unsigned)(t - 1), Bh, tid);
    }
    // Drain staging loads (Bxf) for every wave before the barrier.
    asm volatile("s_waitcnt vmcnt(0)" ::: "memory");
    __syncthreads();

    // ---- Phase B: hg = W_hh(slab) @ h ; convert Bxf(f32) -> Bx(bf16) ----
    {
      f32x4 acc = mfma_slab(a_hh, Bh, bt, n16, quad);
#pragma unroll
      for (int r = 0; r < 4; ++r)
        hg[rt][quad * 4 + r][bt * 16 + n16] = acc[r];
    }
    if (t + 1 < T_SEQ && tid < 256) {
#pragma unroll
      for (int i = 0; i < 16; ++i) {
        const int c16 = i * 8 + sp;
        const float4 f = *(const float4*)(&Bxf[sb][c16 * 4]);
        ushort4 u;
        u.x = f2bf(f.x); u.y = f2bf(f.y); u.z = f2bf(f.z); u.w = f2bf(f.w);
        *(ushort4*)(&Bx[sb][c16 * 4]) = u;
      }
    }
    __syncthreads();

    // ---- Phase C: gates + publish h slice into local L2 ----
    if (tid < 256) {
      float h2[2];
#pragma unroll
      for (int jj = 0; jj < 2; ++jj) {
        const int col = 2 * sp + jj;
        const float xr = xg[0][col][sb], xz = xg[1][col][sb], xn = xg[2][col][sb];
        const float hr = hg[0][col][sb] + bhh_l[col];
        const float hz = hg[1][col][sb] + bhh_l[16 + col];
        const float hn = hg[2][col][sb] + bhh_l[32 + col];
        const float r = 1.f / (1.f + __expf(-(xr + hr)));
        const float z = 1.f / (1.f + __expf(-(xz + hz)));
        const float aa = xn + r * hn;
        const float e = __expf(-2.f * fabsf(aa));
        float th = (1.f - e) / (1.f + e);
        th = copysignf(th, aa);
        const float hp = own_h[col][sb];
        const float hnew = (1.f - z) * th + z * hp;
        own_h[col][sb] = hnew;
        h2[jj] = hnew;
      }
      // tagged bf16 pair -> exchange ring (plain store; lands in shared L2)
      const unsigned int lo =
          (unsigned int)f2bf(h2[0]) | ((unsigned int)f2bf(h2[1]) << 16);
      const unsigned long long val =
          ((unsigned long long)(TAGB + (unsigned)t) << 32) | lo;
      __hip_atomic_store(hx + (long)(t & (SLOTS - 1)) * BATCH * (HSZ / 2) +
                             sb * (HSZ / 2) + g * 8 + sp,
                         val, __ATOMIC_RELAXED, __HIP_MEMORY_SCOPE_WORKGROUP);
      // fp32 result -> out (write-only; off the critical path)
      const unsigned long long o2 =
          ((unsigned long long)__float_as_uint(h2[1]) << 32) |
          (unsigned long long)__float_as_uint(h2[0]);
      __builtin_nontemporal_store(
          o2, (unsigned long long*)(out + (long)sb * T_SEQ * HSZ +
                                    (long)t * HSZ + c0 + 2 * sp));
    }
    __syncthreads();  // xg about to be overwritten by Phase D

    // ---- Phase D: xg(t+1) = W_ih(slab) @ in(t+1)  (Bx already staged) ----
    if (t + 1 < T_SEQ) {
      f32x4 acc = mfma_slab(a_ih, Bx, bt, n16, quad);
#pragma unroll
      for (int r = 0; r < 4; ++r)
        xg[rt][quad * 4 + r][bt * 16 + n16] =
            acc[r] + bih_l[rt * 16 + quad * 4 + r];
      __syncthreads();
    }
  }
}

extern "C" void kernel_launch(void* const* d_in, const int* in_sizes, int n_in,
                              void* d_out, int out_size, void* d_ws, size_t ws_size,
                              hipStream_t stream) {
  const float* in  = (const float*)d_in[0];
  const float* h0  = (const float*)d_in[1];
  const float* wih = (const float*)d_in[2];
  const float* whh = (const float*)d_in[3];
  const float* bih = (const float*)d_in[4];
  const float* bhh = (const float*)d_in[5];
  float* out = (float*)d_out;
  unsigned int* ctl = (unsigned int*)d_ws;  // [0]=target xcd+1, [1]=claim ctr
  unsigned long long* hx =
      (unsigned long long*)((char*)d_ws + CTL_BYTES);  // 2*32*256*8 = 128 KB

  // Zero the control page (stream-ordered; graph-capture legal).
  hipMemsetAsync(d_ws, 0, CTL_BYTES, stream);

  gru_persistent<<<dim3(256), dim3(384), 0, stream>>>(in, h0, wih, whh, bih,
                                                      bhh, out, ctl, hx);
}